// Round 11
// baseline (548.176 us; speedup 1.0000x reference)
//
#include <hip/hip_runtime.h>
#include <cstddef>

#define N_NODES 50000
#define N_EDGES 800000
#define N_GRAPHS 128
#define DIM 128
#define N_LAYERS 4
#define GN_EPS 1e-5f

// bucket-sort params
#define B_CHUNK 256        // chunk blocks
#define EPB 3125           // edges per chunk (256*3125 = 800000 exactly)
#define BUCKET_SHIFT 9
#define BUCKET_SIZE 512
#define NB 98              // ceil(50000/512)

// setup_misc grid partition
#define CX_BLKS 12500      // convert_x: 50000*64 uints / 256
#define CW_BLKS 512        // convert_w: 8*128*128 / 256
#define GB_BLKS 196        // graph_bounds: ceil(50000/256)
#define SETUP_BLKS (CX_BLKS + CW_BLKS + GB_BLKS + B_CHUNK)

typedef unsigned short ushort_t;
typedef __attribute__((ext_vector_type(8))) short frag8;
typedef __attribute__((ext_vector_type(4))) float f32x4;

__device__ inline float bfbits2f(unsigned hi16) { return __uint_as_float(hi16 << 16); }
__device__ inline ushort_t bf16rne(float v) {
    unsigned u = __float_as_uint(v);
    unsigned r = u + 0x7fff + ((u >> 16) & 1);
    return (ushort_t)(r >> 16);
}
__device__ inline unsigned packbf2(float a, float b) {
    return (unsigned)bf16rne(a) | ((unsigned)bf16rne(b) << 16);
}
__device__ inline void bf16split(float v, ushort_t& h, ushort_t& l) {
    ushort_t hi = bf16rne(v);
    float fh = __uint_as_float(((unsigned)hi) << 16);
    l = bf16rne(v - fh);
    h = hi;
}

// ---------------- merged independent setup: convert_x | convert_w | graph_bounds | p1_count ----
__global__ __launch_bounds__(256) void setup_misc(const float* __restrict__ x, unsigned* __restrict__ Hb,
                                                  const float* __restrict__ w1, const float* __restrict__ w2,
                                                  ushort_t* __restrict__ whi, ushort_t* __restrict__ wlo,
                                                  const int* __restrict__ batch, int* __restrict__ gstart,
                                                  const int* __restrict__ edst, int* __restrict__ cnts) {
    __shared__ int cnt[NB];
    int b = blockIdx.x, t = threadIdx.x;
    if (b < CX_BLKS) {
        int i = b * 256 + t;
        if (i < N_NODES * 64) {
            float a = x[2 * i], bb = x[2 * i + 1];
            Hb[i] = packbf2(a, bb);
        }
    } else if (b < CX_BLKS + CW_BLKS) {
        int idx = (b - CX_BLKS) * 256 + t;
        int mat = idx >> 14;
        int e = idx & 16383;
        int n = e >> 7, k = e & 127;
        int l = mat >> 1;
        const float* src = (mat & 1) ? (w2 + (size_t)l * DIM * DIM) : (w1 + (size_t)l * DIM * DIM);
        float v = src[k * DIM + n];
        ushort_t h, lw;
        bf16split(v, h, lw);
        whi[(size_t)mat * DIM * DIM + n * DIM + k] = h;
        wlo[(size_t)mat * DIM * DIM + n * DIM + k] = lw;
    } else if (b < CX_BLKS + CW_BLKS + GB_BLKS) {
        int i = (b - CX_BLKS - CW_BLKS) * 256 + t;
        if (i < N_NODES) {
            int bb = batch[i];
            if (i == 0) {
                for (int g = 0; g <= bb; ++g) gstart[g] = 0;
            } else {
                int pb = batch[i - 1];
                for (int g = pb + 1; g <= bb; ++g) gstart[g] = i;
            }
            if (i == N_NODES - 1) {
                for (int g = bb + 1; g <= N_GRAPHS; ++g) gstart[g] = N_NODES;
            }
        }
    } else {
        int blk = b - (CX_BLKS + CW_BLKS + GB_BLKS);
        for (int i = t; i < NB; i += 256) cnt[i] = 0;
        __syncthreads();
        int base = blk * EPB;
        for (int i = t; i < EPB; i += 256) atomicAdd(&cnt[edst[base + i] >> BUCKET_SHIFT], 1);
        __syncthreads();
        for (int i = t; i < NB; i += 256) cnts[i * B_CHUNK + blk] = cnt[i];
    }
}

// ---------------- scan phase 1 (over NB*B_CHUNK = 25088) ----------------
__global__ __launch_bounds__(1024) void scan_local(const int* __restrict__ in, int* __restrict__ out,
                                                   int* __restrict__ bsum, int n) {
    __shared__ int wsum[16];
    int tid = threadIdx.x, lane = tid & 63, w = tid >> 6;
    int gi = blockIdx.x * 1024 + tid;
    int v = (gi < n) ? in[gi] : 0;
    int s = v;
    #pragma unroll
    for (int off = 1; off < 64; off <<= 1) {
        int t = __shfl_up(s, off, 64);
        if (lane >= off) s += t;
    }
    if (lane == 63) wsum[w] = s;
    __syncthreads();
    if (w == 0) {
        int ws = (lane < 16) ? wsum[lane] : 0;
        #pragma unroll
        for (int off = 1; off < 16; off <<= 1) {
            int t = __shfl_up(ws, off, 64);
            if (lane >= off) ws += t;
        }
        if (lane < 16) wsum[lane] = ws;
    }
    __syncthreads();
    int woff = (w > 0) ? wsum[w - 1] : 0;
    if (gi < n) out[gi] = woff + s - v;
    if (tid == 1023) bsum[blockIdx.x] = woff + s;
}

// ---------------- scan phase 2: each wave redundantly reduces bsum[0..bid) via butterfly ----
__global__ __launch_bounds__(1024) void scan_add(int* __restrict__ out, const int* __restrict__ bsum,
                                                 int n, int total) {
    int lane = threadIdx.x & 63;
    int v = (lane < (int)blockIdx.x) ? bsum[lane] : 0;  // SCAN_BLKS <= 64
    #pragma unroll
    for (int off = 1; off < 64; off <<= 1) v += __shfl_xor(v, off, 64);
    int gi = blockIdx.x * 1024 + threadIdx.x;
    if (gi < n) out[gi] += v;
    if (blockIdx.x == 0 && threadIdx.x == 0) out[n] = total;
}

// ---------------- bucket CSR phase 3: place packed (dstfine<<16 | src) into bucket-major ebuf ----
__global__ __launch_bounds__(256) void p3_place(const int* __restrict__ src, const int* __restrict__ dst,
                                                const int* __restrict__ off, unsigned* __restrict__ ebuf) {
    __shared__ int cur[NB];
    int t = threadIdx.x, blk = blockIdx.x;
    for (int i = t; i < NB; i += 256) cur[i] = off[i * B_CHUNK + blk];
    __syncthreads();
    int base = blk * EPB;
    for (int i = t; i < EPB; i += 256) {
        int d = dst[base + i];
        int b = d >> BUCKET_SHIFT;
        int pos = atomicAdd(&cur[b], 1);
        ebuf[pos] = (unsigned)src[base + i] | ((unsigned)(d & (BUCKET_SIZE - 1)) << 16);
    }
}

// ---------------- bucket CSR phase 4: per-bucket counting sort -> eoff + csr ----------------
__global__ __launch_bounds__(512) void p4_csr(const unsigned* __restrict__ ebuf, const int* __restrict__ off,
                                              int* __restrict__ eoff, int* __restrict__ csr) {
    __shared__ int cnt[BUCKET_SIZE];
    __shared__ int wsum[8];
    int k = blockIdx.x, t = threadIdx.x;
    int bstart = off[k * B_CHUNK];
    int bend = off[(k + 1) * B_CHUNK];
    cnt[t] = 0;
    __syncthreads();
    for (int i = bstart + t; i < bend; i += 512) atomicAdd(&cnt[ebuf[i] >> 16], 1);
    __syncthreads();
    int lane = t & 63, w = t >> 6;
    int v = cnt[t], s = v;
    #pragma unroll
    for (int o = 1; o < 64; o <<= 1) {
        int tt = __shfl_up(s, o, 64);
        if (lane >= o) s += tt;
    }
    if (lane == 63) wsum[w] = s;
    __syncthreads();
    if (w == 0) {
        int ws = (lane < 8) ? wsum[lane] : 0;
        #pragma unroll
        for (int o = 1; o < 8; o <<= 1) {
            int tt = __shfl_up(ws, o, 64);
            if (lane >= o) ws += tt;
        }
        if (lane < 8) wsum[lane] = ws;
    }
    __syncthreads();
    int woff = (w > 0) ? wsum[w - 1] : 0;
    int excl = woff + s - v;
    int node = k * BUCKET_SIZE + t;
    if (node < N_NODES) eoff[node] = bstart + excl;
    __syncthreads();
    cnt[t] = excl;  // reuse as cursor
    __syncthreads();
    for (int i = bstart + t; i < bend; i += 512) {
        unsigned p = ebuf[i];
        int pos = atomicAdd(&cnt[p >> 16], 1);
        csr[bstart + pos] = (int)(p & 0xffffu);
    }
    if (k == NB - 1 && t == 0) eoff[N_NODES] = N_EDGES;
}

// ---------------- fused layer: GIN gather + Zb = relu(relu(T@W1+b1)@W2+b2) ----------
// 256-row tile, 512 threads (8 waves), 96 KB LDS. Each wave gathers its 32 rows'
// neighbor sums (quarter-wave scheme, wave-uniform trip counts) directly into the
// swizzled As; W1h staging is issued first so it overlaps the gather.
__global__ __launch_bounds__(512) void mm_layer(const uint4* __restrict__ h4,
                                                const int* __restrict__ eoff, const int* __restrict__ csr,
                                                const ushort_t* __restrict__ W1h, const ushort_t* __restrict__ W1l,
                                                const ushort_t* __restrict__ W2h, const ushort_t* __restrict__ W2l,
                                                const float* __restrict__ b1, const float* __restrict__ b2,
                                                ushort_t* __restrict__ Zb) {
    __shared__ ushort_t As[256 * 128];   // 64 KB
    __shared__ ushort_t Ws[128 * 128];   // 32 KB
    int tid = threadIdx.x;
    int row0 = blockIdx.x * 256;
    int wave = tid >> 6, lane = tid & 63;   // wave 0..7, each owns 32 rows
    int q = lane >> 4, mn = lane & 15;
    int qtr = lane >> 4, ql = lane & 15;    // gather-phase aliases

    auto stageW = [&](const ushort_t* src) {   // 2048 chunks, 512 thr -> 4 iters
        #pragma unroll
        for (int i = 0; i < 4; ++i) {
            int c = tid + i * 512;
            int r = c >> 4, c8 = c & 15;
            uint4 v = *(const uint4*)(src + r * DIM + c8 * 8);
            *(uint4*)(&Ws[r * 128 + (c8 ^ (r & 7)) * 8]) = v;
        }
    };

    // issue W1h stage first: overlaps the gather below (independent LDS regions)
    stageW(W1h);

    // ---- gather phase: T rows for this block's 256 nodes -> swizzled As ----
    for (int rr = 0; rr < 32; ++rr) {
        int rloc = wave * 32 + rr;
        int node = row0 + rloc;          // wave-uniform
        float a[8];
        #pragma unroll
        for (int k = 0; k < 8; ++k) a[k] = 0.f;

        auto acc_row = [&](uint4 w) {
            a[0] += bfbits2f(w.x & 0xffffu); a[1] += bfbits2f(w.x >> 16);
            a[2] += bfbits2f(w.y & 0xffffu); a[3] += bfbits2f(w.y >> 16);
            a[4] += bfbits2f(w.z & 0xffffu); a[5] += bfbits2f(w.z >> 16);
            a[6] += bfbits2f(w.w & 0xffffu); a[7] += bfbits2f(w.w >> 16);
        };

        if (node < N_NODES) {            // wave-uniform branch
            int lo = eoff[node], hi = eoff[node + 1];
            if (qtr == 0) acc_row(h4[(size_t)node * 16 + ql]);  // self term
            for (int base = lo; base < hi; base += 64) {
                int nav = hi - base;
                if (nav > 64) nav = 64;
                int jv = (base + lane < hi) ? csr[base + lane] : 0;
                int cmin = nav >> 2;
                int cmax = (nav + 3) >> 2;   // uniform loop bounds
                int i = 0;
                for (; i + 3 < cmin; i += 4) {  // 16 gathers in flight
                    int j0 = __shfl(jv, 4 * (i + 0) + qtr, 64);
                    int j1 = __shfl(jv, 4 * (i + 1) + qtr, 64);
                    int j2 = __shfl(jv, 4 * (i + 2) + qtr, 64);
                    int j3 = __shfl(jv, 4 * (i + 3) + qtr, 64);
                    uint4 w0 = h4[(size_t)j0 * 16 + ql];
                    uint4 w1 = h4[(size_t)j1 * 16 + ql];
                    uint4 w2 = h4[(size_t)j2 * 16 + ql];
                    uint4 w3 = h4[(size_t)j3 * 16 + ql];
                    acc_row(w0); acc_row(w1); acc_row(w2); acc_row(w3);
                }
                for (; i < cmin; ++i) {
                    int j = __shfl(jv, 4 * i + qtr, 64);
                    acc_row(h4[(size_t)j * 16 + ql]);
                }
                for (; i < cmax; ++i) {      // tail: shfl BEFORE the predicate
                    int epos = 4 * i + qtr;
                    int j = __shfl(jv, epos, 64);
                    if (epos < nav) acc_row(h4[(size_t)j * 16 + ql]);
                }
            }
        }
        // cross-quarter combine (all lanes active)
        #pragma unroll
        for (int k = 0; k < 8; ++k) {
            a[k] += __shfl_down(a[k], 32, 64);
            a[k] += __shfl_down(a[k], 16, 64);
        }
        if (qtr == 0) {
            uint4 o;
            o.x = packbf2(a[0], a[1]);
            o.y = packbf2(a[2], a[3]);
            o.z = packbf2(a[4], a[5]);
            o.w = packbf2(a[6], a[7]);
            *(uint4*)(&As[rloc * 128 + ((ql ^ (rloc & 7)) * 8)]) = o;
        }
    }

    f32x4 acc[2][8];
    #pragma unroll
    for (int t = 0; t < 2; ++t)
        #pragma unroll
        for (int n = 0; n < 8; ++n) acc[t][n] = (f32x4)(0.f);

    auto compute = [&]() {
        #pragma unroll
        for (int ks = 0; ks < 4; ++ks) {
            int m0 = wave * 32 + mn;
            int m1 = m0 + 16;
            frag8 a0 = *(const frag8*)&As[m0 * 128 + (((ks * 4 + q) ^ (m0 & 7)) * 8)];
            frag8 a1 = *(const frag8*)&As[m1 * 128 + (((ks * 4 + q) ^ (m1 & 7)) * 8)];
            #pragma unroll
            for (int n = 0; n < 8; ++n) {
                int nr = n * 16 + mn;
                frag8 b = *(const frag8*)&Ws[nr * 128 + (((ks * 4 + q) ^ (nr & 7)) * 8)];
                acc[0][n] = __builtin_amdgcn_mfma_f32_16x16x32_bf16(a0, b, acc[0][n], 0, 0, 0);
                acc[1][n] = __builtin_amdgcn_mfma_f32_16x16x32_bf16(a1, b, acc[1][n], 0, 0, 0);
            }
        }
    };

    // ---- GEMM 1: Z1 = relu(T@W1 + b1) ----
    __syncthreads(); compute(); __syncthreads();
    stageW(W1l);
    __syncthreads(); compute(); __syncthreads();

    // epilogue 1: write bf16 Z1 back into As (swizzled), reset acc
    int mloc = wave * 32;
    #pragma unroll
    for (int t = 0; t < 2; ++t) {
        #pragma unroll
        for (int n = 0; n < 8; ++n) {
            int col = n * 16 + mn;
            float bv = b1[col];
            #pragma unroll
            for (int r = 0; r < 4; ++r) {
                int rloc = mloc + t * 16 + q * 4 + r;
                float v = fmaxf(acc[t][n][r] + bv, 0.f);
                As[rloc * 128 + ((col >> 3) ^ (rloc & 7)) * 8 + (col & 7)] = bf16rne(v);
                acc[t][n][r] = 0.f;
            }
        }
    }
    __syncthreads();
    // ---- GEMM 2: Z = relu(Z1@W2 + b2) ----
    stageW(W2h);
    __syncthreads(); compute(); __syncthreads();
    stageW(W2l);
    __syncthreads(); compute();

    // epilogue 2: bf16 streaming store
    #pragma unroll
    for (int t = 0; t < 2; ++t) {
        #pragma unroll
        for (int n = 0; n < 8; ++n) {
            int col = n * 16 + mn;
            float bv = b2[col];
            #pragma unroll
            for (int r = 0; r < 4; ++r) {
                int grow = row0 + mloc + t * 16 + q * 4 + r;
                if (grow < N_NODES)
                    Zb[(size_t)grow * DIM + col] = bf16rne(fmaxf(acc[t][n][r] + bv, 0.f));
            }
        }
    }
}

// ---------------- fused GraphNorm (non-last), DIM-SPLIT: 2 blocks per graph ----------------
__global__ __launch_bounds__(1024) void gn_fused(const unsigned* __restrict__ Zb, const int* __restrict__ gstart,
                                                 const float* __restrict__ scale, const float* __restrict__ weight,
                                                 const float* __restrict__ bias,
                                                 unsigned* __restrict__ Hb) {
    __shared__ float2 sh1[1024], sh2[1024];
    __shared__ float sa[64], sb[64];
    int g = blockIdx.x >> 1, half = blockIdx.x & 1;
    int dpl = threadIdx.x & 31, rg = threadIdx.x >> 5;
    int dp = half * 32 + dpl;
    int s = gstart[g], e = gstart[g + 1];
    float2 s1 = make_float2(0.f, 0.f), s2 = make_float2(0.f, 0.f);
    for (int n = s + rg; n < e; n += 32) {
        unsigned zz = Zb[(size_t)n * 64 + dp];
        float z0 = bfbits2f(zz & 0xffffu), z1 = bfbits2f(zz >> 16);
        s1.x += z0; s1.y += z1;
        s2.x += z0 * z0; s2.y += z1 * z1;
    }
    sh1[threadIdx.x] = s1;
    sh2[threadIdx.x] = s2;
    __syncthreads();
    if (rg == 0) {
        #pragma unroll
        for (int k = 1; k < 32; ++k) {
            float2 t1 = sh1[dpl + 32 * k], t2 = sh2[dpl + 32 * k];
            s1.x += t1.x; s1.y += t1.y;
            s2.x += t2.x; s2.y += t2.y;
        }
        int cnt = e - s;
        float cf = (float)(cnt > 0 ? cnt : 1);
        int d0 = dp * 2, d1 = d0 + 1;
        float m0 = s1.x / cf, m1 = s1.y / cf;
        float ez0 = s2.x / cf, ez1 = s2.y / cf;
        float sc0 = scale[d0], sc1 = scale[d1];
        float var0 = fmaxf(ez0 - (2.0f - sc0) * sc0 * m0 * m0, 0.f);
        float var1 = fmaxf(ez1 - (2.0f - sc1) * sc1 * m1 * m1, 0.f);
        sa[dpl * 2] = m0 * sc0;
        sa[dpl * 2 + 1] = m1 * sc1;
        sb[dpl * 2] = weight[d0] / sqrtf(var0 + GN_EPS);
        sb[dpl * 2 + 1] = weight[d1] / sqrtf(var1 + GN_EPS);
    }
    __syncthreads();
    float as0 = sa[dpl * 2], bm0 = sb[dpl * 2], bi0 = bias[dp * 2];
    float as1 = sa[dpl * 2 + 1], bm1 = sb[dpl * 2 + 1], bi1 = bias[dp * 2 + 1];
    for (int n = s + rg; n < e; n += 32) {
        unsigned zz = Zb[(size_t)n * 64 + dp];
        float z0 = bfbits2f(zz & 0xffffu), z1 = bfbits2f(zz >> 16);
        float o0 = fmaxf((z0 - as0) * bm0 + bi0, 0.f);
        float o1 = fmaxf((z1 - as1) * bm1 + bi1, 0.f);
        Hb[(size_t)n * 64 + dp] = packbf2(o0, o1);
    }
}

// ---------------- last layer: GraphNorm + relu + readout + final MLP + log_softmax ----------
__global__ __launch_bounds__(1024) void gn_last(const unsigned* __restrict__ Zb, const int* __restrict__ gstart,
                                                const float* __restrict__ scale, const float* __restrict__ weight,
                                                const float* __restrict__ bias,
                                                const float* __restrict__ fw1, const float* __restrict__ fb1,
                                                const float* __restrict__ fw2, const float* __restrict__ fb2,
                                                const float* __restrict__ fw3, const float* __restrict__ fb3,
                                                float* __restrict__ out) {
    __shared__ float2 sh1[1024], sh2[1024];
    __shared__ float sa[128], sb[128];
    __shared__ float v0[128], v1[128], v2[128], lg[10];
    int g = blockIdx.x;
    int t = threadIdx.x;
    int dp = t & 63, rg = t >> 6;
    int s = gstart[g], e = gstart[g + 1];
    float2 s1 = make_float2(0.f, 0.f), s2 = make_float2(0.f, 0.f);
    for (int n = s + rg; n < e; n += 16) {
        unsigned zz = Zb[(size_t)n * 64 + dp];
        float z0 = bfbits2f(zz & 0xffffu), z1 = bfbits2f(zz >> 16);
        s1.x += z0; s1.y += z1;
        s2.x += z0 * z0; s2.y += z1 * z1;
    }
    sh1[t] = s1;
    sh2[t] = s2;
    __syncthreads();
    if (rg == 0) {
        #pragma unroll
        for (int k = 1; k < 16; ++k) {
            float2 t1 = sh1[dp + 64 * k], t2 = sh2[dp + 64 * k];
            s1.x += t1.x; s1.y += t1.y;
            s2.x += t2.x; s2.y += t2.y;
        }
        int cnt = e - s;
        float cf = (float)(cnt > 0 ? cnt : 1);
        int d0 = dp * 2, d1 = d0 + 1;
        float m0 = s1.x / cf, m1 = s1.y / cf;
        float ez0 = s2.x / cf, ez1 = s2.y / cf;
        float sc0 = scale[d0], sc1 = scale[d1];
        float var0 = fmaxf(ez0 - (2.0f - sc0) * sc0 * m0 * m0, 0.f);
        float var1 = fmaxf(ez1 - (2.0f - sc1) * sc1 * m1 * m1, 0.f);
        sa[d0] = m0 * sc0;
        sa[d1] = m1 * sc1;
        sb[d0] = weight[d0] / sqrtf(var0 + GN_EPS);
        sb[d1] = weight[d1] / sqrtf(var1 + GN_EPS);
    }
    __syncthreads();
    int d0 = dp * 2, d1 = d0 + 1;
    float as0 = sa[d0], bm0 = sb[d0], bi0 = bias[d0];
    float as1 = sa[d1], bm1 = sb[d1], bi1 = bias[d1];
    float2 rsum = make_float2(0.f, 0.f);
    for (int n = s + rg; n < e; n += 16) {
        unsigned zz = Zb[(size_t)n * 64 + dp];
        float z0 = bfbits2f(zz & 0xffffu), z1 = bfbits2f(zz >> 16);
        rsum.x += fmaxf((z0 - as0) * bm0 + bi0, 0.f);
        rsum.y += fmaxf((z1 - as1) * bm1 + bi1, 0.f);
    }
    __syncthreads();
    sh1[t] = rsum;
    __syncthreads();
    if (rg == 0) {
        #pragma unroll
        for (int k = 1; k < 16; ++k) {
            float2 t1 = sh1[dp + 64 * k];
            rsum.x += t1.x; rsum.y += t1.y;
        }
        v0[d0] = rsum.x;
        v0[d1] = rsum.y;
    }
    __syncthreads();
    if (t < 128) {
        float acc = fb1[t];
        for (int d = 0; d < 128; ++d) acc += v0[d] * fw1[d * 128 + t];
        v1[t] = fmaxf(acc, 0.f);
    }
    __syncthreads();
    if (t < 128) {
        float acc = fb2[t];
        for (int d = 0; d < 128; ++d) acc += v1[d] * fw2[d * 128 + t];
        v2[t] = fmaxf(acc, 0.f);
    }
    __syncthreads();
    if (t < 10) {
        float acc = fb3[t];
        for (int d = 0; d < 128; ++d) acc += v2[d] * fw3[d * 10 + t];
        lg[t] = acc;
    }
    __syncthreads();
    if (t < 10) {
        float m = -1e30f;
        for (int c = 0; c < 10; ++c) m = fmaxf(m, lg[c]);
        float ssum = 0.f;
        for (int c = 0; c < 10; ++c) ssum += expf(lg[c] - m);
        out[g * 10 + t] = lg[t] - m - logf(ssum);
    }
}

extern "C" void kernel_launch(void* const* d_in, const int* in_sizes, int n_in,
                              void* d_out, int out_size, void* d_ws, size_t ws_size,
                              hipStream_t stream) {
    const float* x      = (const float*)d_in[0];
    const float* gin_w1 = (const float*)d_in[1];
    const float* gin_b1 = (const float*)d_in[2];
    const float* gin_w2 = (const float*)d_in[3];
    const float* gin_b2 = (const float*)d_in[4];
    const float* gn_w   = (const float*)d_in[5];
    const float* gn_b   = (const float*)d_in[6];
    const float* gn_s   = (const float*)d_in[7];
    const float* fw1    = (const float*)d_in[8];
    const float* fb1    = (const float*)d_in[9];
    const float* fw2    = (const float*)d_in[10];
    const float* fb2    = (const float*)d_in[11];
    const float* fw3    = (const float*)d_in[12];
    const float* fb3    = (const float*)d_in[13];
    const int*   eidx   = (const int*)d_in[14];
    const int*   batch  = (const int*)d_in[15];
    float* out = (float*)d_out;

    const int* esrc = eidx;
    const int* edst = eidx + N_EDGES;

    auto align_up = [](size_t v) { return (v + 255) & ~(size_t)255; };
    char* p = (char*)d_ws;
    unsigned* Hb = (unsigned*)p;   p += align_up((size_t)N_NODES * DIM * 2);
    unsigned* Zb = (unsigned*)p;   p += align_up((size_t)N_NODES * DIM * 2);
    ushort_t* WThi = (ushort_t*)p; p += align_up((size_t)8 * DIM * DIM * 2);
    ushort_t* WTlo = (ushort_t*)p; p += align_up((size_t)8 * DIM * DIM * 2);
    int* gstart = (int*)p;         p += align_up((N_GRAPHS + 1) * 4);
    int* cnts = (int*)p;           p += align_up((size_t)NB * B_CHUNK * 4);
    int* off = (int*)p;            p += align_up(((size_t)NB * B_CHUNK + 1) * 4);
    int* bsum = (int*)p;           p += align_up(64 * 4);
    unsigned* ebuf = (unsigned*)p; p += align_up((size_t)N_EDGES * 4);
    int* eoff = (int*)p;           p += align_up((N_NODES + 1) * 4);
    int* csr = (int*)p;            p += align_up((size_t)N_EDGES * 4);

    const int SCAN_N = NB * B_CHUNK;                      // 25088
    const int SCAN_BLKS = (SCAN_N + 1023) / 1024;         // 25 (<= 64 for scan_add butterfly)
    setup_misc<<<SETUP_BLKS, 256, 0, stream>>>(x, Hb, gin_w1, gin_w2, WThi, WTlo,
                                               batch, gstart, edst, cnts);
    scan_local<<<SCAN_BLKS, 1024, 0, stream>>>(cnts, off, bsum, SCAN_N);
    scan_add<<<SCAN_BLKS, 1024, 0, stream>>>(off, bsum, SCAN_N, N_EDGES);
    p3_place<<<B_CHUNK, 256, 0, stream>>>(esrc, edst, off, ebuf);
    p4_csr<<<NB, 512, 0, stream>>>(ebuf, off, eoff, csr);

    const int mm_grid = (N_NODES + 255) / 256;  // 196 blocks <= 256 CUs
    for (int l = 0; l < N_LAYERS; ++l) {
        mm_layer<<<mm_grid, 512, 0, stream>>>((const uint4*)Hb, eoff, csr,
            WThi + (size_t)(2 * l) * DIM * DIM, WTlo + (size_t)(2 * l) * DIM * DIM,
            WThi + (size_t)(2 * l + 1) * DIM * DIM, WTlo + (size_t)(2 * l + 1) * DIM * DIM,
            gin_b1 + l * DIM, gin_b2 + l * DIM, (ushort_t*)Zb);
        if (l == N_LAYERS - 1)
            gn_last<<<N_GRAPHS, 1024, 0, stream>>>(Zb, gstart, gn_s + l * DIM,
                gn_w + l * DIM, gn_b + l * DIM, fw1, fb1, fw2, fb2, fw3, fb3, out);
        else
            gn_fused<<<N_GRAPHS * 2, 1024, 0, stream>>>(Zb, gstart, gn_s + l * DIM,
                gn_w + l * DIM, gn_b + l * DIM, Hb);
    }
}

// Round 12
// 386.877 us; speedup vs baseline: 1.4169x; 1.4169x over previous
//
#include <hip/hip_runtime.h>
#include <cstddef>

#define N_NODES 50000
#define N_EDGES 800000
#define N_GRAPHS 128
#define DIM 128
#define N_LAYERS 4
#define GN_EPS 1e-5f

// bucket-sort params
#define B_CHUNK 256        // chunk blocks
#define EPB 3125           // edges per chunk (256*3125 = 800000 exactly)
#define BUCKET_SHIFT 9
#define BUCKET_SIZE 512
#define NB 98              // ceil(50000/512)

// setup_misc grid partition
#define CX_BLKS 12500      // convert_x: 50000*64 uints / 256
#define CW_BLKS 512        // convert_w: 8*128*128 / 256
#define GB_BLKS 196        // graph_bounds: ceil(50000/256)
#define SETUP_BLKS (CX_BLKS + CW_BLKS + GB_BLKS + B_CHUNK)

typedef unsigned short ushort_t;
typedef __attribute__((ext_vector_type(8))) short frag8;
typedef __attribute__((ext_vector_type(4))) float f32x4;

__device__ inline float bfbits2f(unsigned hi16) { return __uint_as_float(hi16 << 16); }
__device__ inline ushort_t bf16rne(float v) {
    unsigned u = __float_as_uint(v);
    unsigned r = u + 0x7fff + ((u >> 16) & 1);
    return (ushort_t)(r >> 16);
}
__device__ inline unsigned packbf2(float a, float b) {
    return (unsigned)bf16rne(a) | ((unsigned)bf16rne(b) << 16);
}
__device__ inline void bf16split(float v, ushort_t& h, ushort_t& l) {
    ushort_t hi = bf16rne(v);
    float fh = __uint_as_float(((unsigned)hi) << 16);
    l = bf16rne(v - fh);
    h = hi;
}

// ---------------- merged independent setup: convert_x | convert_w | graph_bounds | p1_count ----
__global__ __launch_bounds__(256) void setup_misc(const float* __restrict__ x, unsigned* __restrict__ Hb,
                                                  const float* __restrict__ w1, const float* __restrict__ w2,
                                                  ushort_t* __restrict__ whi, ushort_t* __restrict__ wlo,
                                                  const int* __restrict__ batch, int* __restrict__ gstart,
                                                  const int* __restrict__ edst, int* __restrict__ cnts) {
    __shared__ int cnt[NB];
    int b = blockIdx.x, t = threadIdx.x;
    if (b < CX_BLKS) {
        int i = b * 256 + t;
        if (i < N_NODES * 64) {
            float a = x[2 * i], bb = x[2 * i + 1];
            Hb[i] = packbf2(a, bb);
        }
    } else if (b < CX_BLKS + CW_BLKS) {
        int idx = (b - CX_BLKS) * 256 + t;
        int mat = idx >> 14;
        int e = idx & 16383;
        int n = e >> 7, k = e & 127;
        int l = mat >> 1;
        const float* src = (mat & 1) ? (w2 + (size_t)l * DIM * DIM) : (w1 + (size_t)l * DIM * DIM);
        float v = src[k * DIM + n];
        ushort_t h, lw;
        bf16split(v, h, lw);
        whi[(size_t)mat * DIM * DIM + n * DIM + k] = h;
        wlo[(size_t)mat * DIM * DIM + n * DIM + k] = lw;
    } else if (b < CX_BLKS + CW_BLKS + GB_BLKS) {
        int i = (b - CX_BLKS - CW_BLKS) * 256 + t;
        if (i < N_NODES) {
            int bb = batch[i];
            if (i == 0) {
                for (int g = 0; g <= bb; ++g) gstart[g] = 0;
            } else {
                int pb = batch[i - 1];
                for (int g = pb + 1; g <= bb; ++g) gstart[g] = i;
            }
            if (i == N_NODES - 1) {
                for (int g = bb + 1; g <= N_GRAPHS; ++g) gstart[g] = N_NODES;
            }
        }
    } else {
        int blk = b - (CX_BLKS + CW_BLKS + GB_BLKS);
        for (int i = t; i < NB; i += 256) cnt[i] = 0;
        __syncthreads();
        int base = blk * EPB;
        for (int i = t; i < EPB; i += 256) atomicAdd(&cnt[edst[base + i] >> BUCKET_SHIFT], 1);
        __syncthreads();
        for (int i = t; i < NB; i += 256) cnts[i * B_CHUNK + blk] = cnt[i];
    }
}

// ---------------- scan phase 1 (over NB*B_CHUNK = 25088) ----------------
__global__ __launch_bounds__(1024) void scan_local(const int* __restrict__ in, int* __restrict__ out,
                                                   int* __restrict__ bsum, int n) {
    __shared__ int wsum[16];
    int tid = threadIdx.x, lane = tid & 63, w = tid >> 6;
    int gi = blockIdx.x * 1024 + tid;
    int v = (gi < n) ? in[gi] : 0;
    int s = v;
    #pragma unroll
    for (int off = 1; off < 64; off <<= 1) {
        int t = __shfl_up(s, off, 64);
        if (lane >= off) s += t;
    }
    if (lane == 63) wsum[w] = s;
    __syncthreads();
    if (w == 0) {
        int ws = (lane < 16) ? wsum[lane] : 0;
        #pragma unroll
        for (int off = 1; off < 16; off <<= 1) {
            int t = __shfl_up(ws, off, 64);
            if (lane >= off) ws += t;
        }
        if (lane < 16) wsum[lane] = ws;
    }
    __syncthreads();
    int woff = (w > 0) ? wsum[w - 1] : 0;
    if (gi < n) out[gi] = woff + s - v;
    if (tid == 1023) bsum[blockIdx.x] = woff + s;
}

// ---------------- scan phase 2: each wave redundantly reduces bsum[0..bid) via butterfly ----
__global__ __launch_bounds__(1024) void scan_add(int* __restrict__ out, const int* __restrict__ bsum,
                                                 int n, int total) {
    int lane = threadIdx.x & 63;
    int v = (lane < (int)blockIdx.x) ? bsum[lane] : 0;  // SCAN_BLKS <= 64
    #pragma unroll
    for (int off = 1; off < 64; off <<= 1) v += __shfl_xor(v, off, 64);
    int gi = blockIdx.x * 1024 + threadIdx.x;
    if (gi < n) out[gi] += v;
    if (blockIdx.x == 0 && threadIdx.x == 0) out[n] = total;
}

// ---------------- bucket CSR phase 3: place packed (dstfine<<16 | src) into bucket-major ebuf ----
__global__ __launch_bounds__(256) void p3_place(const int* __restrict__ src, const int* __restrict__ dst,
                                                const int* __restrict__ off, unsigned* __restrict__ ebuf) {
    __shared__ int cur[NB];
    int t = threadIdx.x, blk = blockIdx.x;
    for (int i = t; i < NB; i += 256) cur[i] = off[i * B_CHUNK + blk];
    __syncthreads();
    int base = blk * EPB;
    for (int i = t; i < EPB; i += 256) {
        int d = dst[base + i];
        int b = d >> BUCKET_SHIFT;
        int pos = atomicAdd(&cur[b], 1);
        ebuf[pos] = (unsigned)src[base + i] | ((unsigned)(d & (BUCKET_SIZE - 1)) << 16);
    }
}

// ---------------- bucket CSR phase 4: per-bucket counting sort -> eoff + csr ----------------
__global__ __launch_bounds__(512) void p4_csr(const unsigned* __restrict__ ebuf, const int* __restrict__ off,
                                              int* __restrict__ eoff, int* __restrict__ csr) {
    __shared__ int cnt[BUCKET_SIZE];
    __shared__ int wsum[8];
    int k = blockIdx.x, t = threadIdx.x;
    int bstart = off[k * B_CHUNK];
    int bend = off[(k + 1) * B_CHUNK];
    cnt[t] = 0;
    __syncthreads();
    for (int i = bstart + t; i < bend; i += 512) atomicAdd(&cnt[ebuf[i] >> 16], 1);
    __syncthreads();
    int lane = t & 63, w = t >> 6;
    int v = cnt[t], s = v;
    #pragma unroll
    for (int o = 1; o < 64; o <<= 1) {
        int tt = __shfl_up(s, o, 64);
        if (lane >= o) s += tt;
    }
    if (lane == 63) wsum[w] = s;
    __syncthreads();
    if (w == 0) {
        int ws = (lane < 8) ? wsum[lane] : 0;
        #pragma unroll
        for (int o = 1; o < 8; o <<= 1) {
            int tt = __shfl_up(ws, o, 64);
            if (lane >= o) ws += tt;
        }
        if (lane < 8) wsum[lane] = ws;
    }
    __syncthreads();
    int woff = (w > 0) ? wsum[w - 1] : 0;
    int excl = woff + s - v;
    int node = k * BUCKET_SIZE + t;
    if (node < N_NODES) eoff[node] = bstart + excl;
    __syncthreads();
    cnt[t] = excl;  // reuse as cursor
    __syncthreads();
    for (int i = bstart + t; i < bend; i += 512) {
        unsigned p = ebuf[i];
        int pos = atomicAdd(&cnt[p >> 16], 1);
        csr[bstart + pos] = (int)(p & 0xffffu);
    }
    if (k == NB - 1 && t == 0) eoff[N_NODES] = N_EDGES;
}

// ---------------- GIN aggregation v4: quarter-wave edge parallelism, uint4 lanes ----------------
// one wave per NODE (50k waves -> full TLP; lesson from R11: do NOT fuse this into the
// low-occupancy GEMM kernel — the gather needs massive wave count to hide latency).
__global__ __launch_bounds__(256) void agg_bf16(const uint4* __restrict__ h4, const int* __restrict__ eoff,
                                                const int* __restrict__ csr, uint4* __restrict__ T4) {
    int wid = (blockIdx.x * 256 + threadIdx.x) >> 6;
    int lane = threadIdx.x & 63;
    int qtr = lane >> 4;
    int ql = lane & 15;
    if (wid >= N_NODES) return;
    int lo = eoff[wid], hi = eoff[wid + 1];

    float a[8];
    #pragma unroll
    for (int k = 0; k < 8; ++k) a[k] = 0.f;

    auto acc_row = [&](uint4 w) {
        a[0] += bfbits2f(w.x & 0xffffu); a[1] += bfbits2f(w.x >> 16);
        a[2] += bfbits2f(w.y & 0xffffu); a[3] += bfbits2f(w.y >> 16);
        a[4] += bfbits2f(w.z & 0xffffu); a[5] += bfbits2f(w.z >> 16);
        a[6] += bfbits2f(w.w & 0xffffu); a[7] += bfbits2f(w.w >> 16);
    };

    if (qtr == 0) acc_row(h4[(size_t)wid * 16 + ql]);  // self term

    for (int base = lo; base < hi; base += 64) {
        int nav = hi - base;
        if (nav > 64) nav = 64;
        int jv = (base + lane < hi) ? csr[base + lane] : 0;  // one coalesced index load
        int cmin = nav >> 2;
        int cmax = (nav + 3) >> 2;   // uniform loop bounds for the whole wave
        int i = 0;
        for (; i + 3 < cmin; i += 4) {  // 16 edges in flight across the wave
            int j0 = __shfl(jv, 4 * (i + 0) + qtr, 64);
            int j1 = __shfl(jv, 4 * (i + 1) + qtr, 64);
            int j2 = __shfl(jv, 4 * (i + 2) + qtr, 64);
            int j3 = __shfl(jv, 4 * (i + 3) + qtr, 64);
            uint4 w0 = h4[(size_t)j0 * 16 + ql];
            uint4 w1 = h4[(size_t)j1 * 16 + ql];
            uint4 w2 = h4[(size_t)j2 * 16 + ql];
            uint4 w3 = h4[(size_t)j3 * 16 + ql];
            acc_row(w0); acc_row(w1); acc_row(w2); acc_row(w3);
        }
        for (; i < cmin; ++i) {
            int j = __shfl(jv, 4 * i + qtr, 64);
            acc_row(h4[(size_t)j * 16 + ql]);
        }
        for (; i < cmax; ++i) {          // partial tail: shfl BEFORE the predicate
            int epos = 4 * i + qtr;
            int j = __shfl(jv, epos, 64);
            if (epos < nav) acc_row(h4[(size_t)j * 16 + ql]);
        }
    }

    #pragma unroll
    for (int k = 0; k < 8; ++k) {
        a[k] += __shfl_down(a[k], 32, 64);
        a[k] += __shfl_down(a[k], 16, 64);
    }
    if (qtr == 0) {
        uint4 o;
        o.x = packbf2(a[0], a[1]);
        o.y = packbf2(a[2], a[3]);
        o.z = packbf2(a[4], a[5]);
        o.w = packbf2(a[6], a[7]);
        T4[(size_t)wid * 16 + ql] = o;
    }
}

// ---------------- fused layer GEMM: 256-row tile, 512 threads (8 waves), 96 KB LDS --------
// Zb = relu(relu(T@W1+b1)@W2+b2); Z1 round-trips through As in LDS.
__global__ __launch_bounds__(512) void mm_layer(const ushort_t* __restrict__ A,
                                                const ushort_t* __restrict__ W1h, const ushort_t* __restrict__ W1l,
                                                const ushort_t* __restrict__ W2h, const ushort_t* __restrict__ W2l,
                                                const float* __restrict__ b1, const float* __restrict__ b2,
                                                ushort_t* __restrict__ Zb) {
    __shared__ ushort_t As[256 * 128];   // 64 KB
    __shared__ ushort_t Ws[128 * 128];   // 32 KB
    int tid = threadIdx.x;
    int row0 = blockIdx.x * 256;
    int wave = tid >> 6, lane = tid & 63;   // wave 0..7, each owns 32 rows
    int q = lane >> 4, mn = lane & 15;

    f32x4 acc[2][8];
    #pragma unroll
    for (int t = 0; t < 2; ++t)
        #pragma unroll
        for (int n = 0; n < 8; ++n) acc[t][n] = (f32x4)(0.f);

    // stage A: 256 rows x 16 uint4-chunks = 4096 chunks, 512 thr -> 8 iters
    #pragma unroll
    for (int i = 0; i < 8; ++i) {
        int c = tid + i * 512;
        int r = c >> 4, c8 = c & 15;
        uint4 v = make_uint4(0u, 0u, 0u, 0u);
        int gr = row0 + r;
        if (gr < N_NODES) v = *(const uint4*)(A + (size_t)gr * DIM + c8 * 8);
        *(uint4*)(&As[r * 128 + (c8 ^ (r & 7)) * 8]) = v;
    }
    auto stageW = [&](const ushort_t* src) {   // 2048 chunks, 512 thr -> 4 iters
        #pragma unroll
        for (int i = 0; i < 4; ++i) {
            int c = tid + i * 512;
            int r = c >> 4, c8 = c & 15;
            uint4 v = *(const uint4*)(src + r * DIM + c8 * 8);
            *(uint4*)(&Ws[r * 128 + (c8 ^ (r & 7)) * 8]) = v;
        }
    };
    auto compute = [&]() {
        #pragma unroll
        for (int ks = 0; ks < 4; ++ks) {
            int m0 = wave * 32 + mn;
            int m1 = m0 + 16;
            frag8 a0 = *(const frag8*)&As[m0 * 128 + (((ks * 4 + q) ^ (m0 & 7)) * 8)];
            frag8 a1 = *(const frag8*)&As[m1 * 128 + (((ks * 4 + q) ^ (m1 & 7)) * 8)];
            #pragma unroll
            for (int n = 0; n < 8; ++n) {
                int nr = n * 16 + mn;
                frag8 b = *(const frag8*)&Ws[nr * 128 + (((ks * 4 + q) ^ (nr & 7)) * 8)];
                acc[0][n] = __builtin_amdgcn_mfma_f32_16x16x32_bf16(a0, b, acc[0][n], 0, 0, 0);
                acc[1][n] = __builtin_amdgcn_mfma_f32_16x16x32_bf16(a1, b, acc[1][n], 0, 0, 0);
            }
        }
    };

    // ---- GEMM 1: Z1 = relu(A@W1 + b1) ----
    stageW(W1h);
    __syncthreads(); compute(); __syncthreads();
    stageW(W1l);
    __syncthreads(); compute(); __syncthreads();

    // epilogue 1: write bf16 Z1 back into As (swizzled), reset acc
    int mloc = wave * 32;
    #pragma unroll
    for (int t = 0; t < 2; ++t) {
        #pragma unroll
        for (int n = 0; n < 8; ++n) {
            int col = n * 16 + mn;
            float bv = b1[col];
            #pragma unroll
            for (int r = 0; r < 4; ++r) {
                int rloc = mloc + t * 16 + q * 4 + r;
                float v = fmaxf(acc[t][n][r] + bv, 0.f);
                As[rloc * 128 + ((col >> 3) ^ (rloc & 7)) * 8 + (col & 7)] = bf16rne(v);
                acc[t][n][r] = 0.f;
            }
        }
    }
    __syncthreads();
    // ---- GEMM 2: Z = relu(Z1@W2 + b2) ----
    stageW(W2h);
    __syncthreads(); compute(); __syncthreads();
    stageW(W2l);
    __syncthreads(); compute();

    // epilogue 2: bf16 streaming store
    #pragma unroll
    for (int t = 0; t < 2; ++t) {
        #pragma unroll
        for (int n = 0; n < 8; ++n) {
            int col = n * 16 + mn;
            float bv = b2[col];
            #pragma unroll
            for (int r = 0; r < 4; ++r) {
                int grow = row0 + mloc + t * 16 + q * 4 + r;
                if (grow < N_NODES)
                    Zb[(size_t)grow * DIM + col] = bf16rne(fmaxf(acc[t][n][r] + bv, 0.f));
            }
        }
    }
}

// ---------------- fused GraphNorm (non-last), DIM-SPLIT: 2 blocks per graph ----------------
__global__ __launch_bounds__(1024) void gn_fused(const unsigned* __restrict__ Zb, const int* __restrict__ gstart,
                                                 const float* __restrict__ scale, const float* __restrict__ weight,
                                                 const float* __restrict__ bias,
                                                 unsigned* __restrict__ Hb) {
    __shared__ float2 sh1[1024], sh2[1024];
    __shared__ float sa[64], sb[64];
    int g = blockIdx.x >> 1, half = blockIdx.x & 1;
    int dpl = threadIdx.x & 31, rg = threadIdx.x >> 5;
    int dp = half * 32 + dpl;
    int s = gstart[g], e = gstart[g + 1];
    float2 s1 = make_float2(0.f, 0.f), s2 = make_float2(0.f, 0.f);
    for (int n = s + rg; n < e; n += 32) {
        unsigned zz = Zb[(size_t)n * 64 + dp];
        float z0 = bfbits2f(zz & 0xffffu), z1 = bfbits2f(zz >> 16);
        s1.x += z0; s1.y += z1;
        s2.x += z0 * z0; s2.y += z1 * z1;
    }
    sh1[threadIdx.x] = s1;
    sh2[threadIdx.x] = s2;
    __syncthreads();
    if (rg == 0) {
        #pragma unroll
        for (int k = 1; k < 32; ++k) {
            float2 t1 = sh1[dpl + 32 * k], t2 = sh2[dpl + 32 * k];
            s1.x += t1.x; s1.y += t1.y;
            s2.x += t2.x; s2.y += t2.y;
        }
        int cnt = e - s;
        float cf = (float)(cnt > 0 ? cnt : 1);
        int d0 = dp * 2, d1 = d0 + 1;
        float m0 = s1.x / cf, m1 = s1.y / cf;
        float ez0 = s2.x / cf, ez1 = s2.y / cf;
        float sc0 = scale[d0], sc1 = scale[d1];
        float var0 = fmaxf(ez0 - (2.0f - sc0) * sc0 * m0 * m0, 0.f);
        float var1 = fmaxf(ez1 - (2.0f - sc1) * sc1 * m1 * m1, 0.f);
        sa[dpl * 2] = m0 * sc0;
        sa[dpl * 2 + 1] = m1 * sc1;
        sb[dpl * 2] = weight[d0] / sqrtf(var0 + GN_EPS);
        sb[dpl * 2 + 1] = weight[d1] / sqrtf(var1 + GN_EPS);
    }
    __syncthreads();
    float as0 = sa[dpl * 2], bm0 = sb[dpl * 2], bi0 = bias[dp * 2];
    float as1 = sa[dpl * 2 + 1], bm1 = sb[dpl * 2 + 1], bi1 = bias[dp * 2 + 1];
    for (int n = s + rg; n < e; n += 32) {
        unsigned zz = Zb[(size_t)n * 64 + dp];
        float z0 = bfbits2f(zz & 0xffffu), z1 = bfbits2f(zz >> 16);
        float o0 = fmaxf((z0 - as0) * bm0 + bi0, 0.f);
        float o1 = fmaxf((z1 - as1) * bm1 + bi1, 0.f);
        Hb[(size_t)n * 64 + dp] = packbf2(o0, o1);
    }
}

// ---------------- last layer: GraphNorm + relu + readout + final MLP + log_softmax ----------
__global__ __launch_bounds__(1024) void gn_last(const unsigned* __restrict__ Zb, const int* __restrict__ gstart,
                                                const float* __restrict__ scale, const float* __restrict__ weight,
                                                const float* __restrict__ bias,
                                                const float* __restrict__ fw1, const float* __restrict__ fb1,
                                                const float* __restrict__ fw2, const float* __restrict__ fb2,
                                                const float* __restrict__ fw3, const float* __restrict__ fb3,
                                                float* __restrict__ out) {
    __shared__ float2 sh1[1024], sh2[1024];
    __shared__ float sa[128], sb[128];
    __shared__ float v0[128], v1[128], v2[128], lg[10];
    int g = blockIdx.x;
    int t = threadIdx.x;
    int dp = t & 63, rg = t >> 6;
    int s = gstart[g], e = gstart[g + 1];
    float2 s1 = make_float2(0.f, 0.f), s2 = make_float2(0.f, 0.f);
    for (int n = s + rg; n < e; n += 16) {
        unsigned zz = Zb[(size_t)n * 64 + dp];
        float z0 = bfbits2f(zz & 0xffffu), z1 = bfbits2f(zz >> 16);
        s1.x += z0; s1.y += z1;
        s2.x += z0 * z0; s2.y += z1 * z1;
    }
    sh1[t] = s1;
    sh2[t] = s2;
    __syncthreads();
    if (rg == 0) {
        #pragma unroll
        for (int k = 1; k < 16; ++k) {
            float2 t1 = sh1[dp + 64 * k], t2 = sh2[dp + 64 * k];
            s1.x += t1.x; s1.y += t1.y;
            s2.x += t2.x; s2.y += t2.y;
        }
        int cnt = e - s;
        float cf = (float)(cnt > 0 ? cnt : 1);
        int d0 = dp * 2, d1 = d0 + 1;
        float m0 = s1.x / cf, m1 = s1.y / cf;
        float ez0 = s2.x / cf, ez1 = s2.y / cf;
        float sc0 = scale[d0], sc1 = scale[d1];
        float var0 = fmaxf(ez0 - (2.0f - sc0) * sc0 * m0 * m0, 0.f);
        float var1 = fmaxf(ez1 - (2.0f - sc1) * sc1 * m1 * m1, 0.f);
        sa[d0] = m0 * sc0;
        sa[d1] = m1 * sc1;
        sb[d0] = weight[d0] / sqrtf(var0 + GN_EPS);
        sb[d1] = weight[d1] / sqrtf(var1 + GN_EPS);
    }
    __syncthreads();
    int d0 = dp * 2, d1 = d0 + 1;
    float as0 = sa[d0], bm0 = sb[d0], bi0 = bias[d0];
    float as1 = sa[d1], bm1 = sb[d1], bi1 = bias[d1];
    float2 rsum = make_float2(0.f, 0.f);
    for (int n = s + rg; n < e; n += 16) {
        unsigned zz = Zb[(size_t)n * 64 + dp];
        float z0 = bfbits2f(zz & 0xffffu), z1 = bfbits2f(zz >> 16);
        rsum.x += fmaxf((z0 - as0) * bm0 + bi0, 0.f);
        rsum.y += fmaxf((z1 - as1) * bm1 + bi1, 0.f);
    }
    __syncthreads();
    sh1[t] = rsum;
    __syncthreads();
    if (rg == 0) {
        #pragma unroll
        for (int k = 1; k < 16; ++k) {
            float2 t1 = sh1[dp + 64 * k];
            rsum.x += t1.x; rsum.y += t1.y;
        }
        v0[d0] = rsum.x;
        v0[d1] = rsum.y;
    }
    __syncthreads();
    if (t < 128) {
        float acc = fb1[t];
        for (int d = 0; d < 128; ++d) acc += v0[d] * fw1[d * 128 + t];
        v1[t] = fmaxf(acc, 0.f);
    }
    __syncthreads();
    if (t < 128) {
        float acc = fb2[t];
        for (int d = 0; d < 128; ++d) acc += v1[d] * fw2[d * 128 + t];
        v2[t] = fmaxf(acc, 0.f);
    }
    __syncthreads();
    if (t < 10) {
        float acc = fb3[t];
        for (int d = 0; d < 128; ++d) acc += v2[d] * fw3[d * 10 + t];
        lg[t] = acc;
    }
    __syncthreads();
    if (t < 10) {
        float m = -1e30f;
        for (int c = 0; c < 10; ++c) m = fmaxf(m, lg[c]);
        float ssum = 0.f;
        for (int c = 0; c < 10; ++c) ssum += expf(lg[c] - m);
        out[g * 10 + t] = lg[t] - m - logf(ssum);
    }
}

extern "C" void kernel_launch(void* const* d_in, const int* in_sizes, int n_in,
                              void* d_out, int out_size, void* d_ws, size_t ws_size,
                              hipStream_t stream) {
    const float* x      = (const float*)d_in[0];
    const float* gin_w1 = (const float*)d_in[1];
    const float* gin_b1 = (const float*)d_in[2];
    const float* gin_w2 = (const float*)d_in[3];
    const float* gin_b2 = (const float*)d_in[4];
    const float* gn_w   = (const float*)d_in[5];
    const float* gn_b   = (const float*)d_in[6];
    const float* gn_s   = (const float*)d_in[7];
    const float* fw1    = (const float*)d_in[8];
    const float* fb1    = (const float*)d_in[9];
    const float* fw2    = (const float*)d_in[10];
    const float* fb2    = (const float*)d_in[11];
    const float* fw3    = (const float*)d_in[12];
    const float* fb3    = (const float*)d_in[13];
    const int*   eidx   = (const int*)d_in[14];
    const int*   batch  = (const int*)d_in[15];
    float* out = (float*)d_out;

    const int* esrc = eidx;
    const int* edst = eidx + N_EDGES;

    auto align_up = [](size_t v) { return (v + 255) & ~(size_t)255; };
    char* p = (char*)d_ws;
    unsigned* Hb = (unsigned*)p;   p += align_up((size_t)N_NODES * DIM * 2);
    unsigned* Tb = (unsigned*)p;   p += align_up((size_t)N_NODES * DIM * 2);
    unsigned* Zb = (unsigned*)p;   p += align_up((size_t)N_NODES * DIM * 2);
    ushort_t* WThi = (ushort_t*)p; p += align_up((size_t)8 * DIM * DIM * 2);
    ushort_t* WTlo = (ushort_t*)p; p += align_up((size_t)8 * DIM * DIM * 2);
    int* gstart = (int*)p;         p += align_up((N_GRAPHS + 1) * 4);
    int* cnts = (int*)p;           p += align_up((size_t)NB * B_CHUNK * 4);
    int* off = (int*)p;            p += align_up(((size_t)NB * B_CHUNK + 1) * 4);
    int* bsum = (int*)p;           p += align_up(64 * 4);
    unsigned* ebuf = (unsigned*)p; p += align_up((size_t)N_EDGES * 4);
    int* eoff = (int*)p;           p += align_up((N_NODES + 1) * 4);
    int* csr = (int*)p;            p += align_up((size_t)N_EDGES * 4);

    const int SCAN_N = NB * B_CHUNK;                      // 25088
    const int SCAN_BLKS = (SCAN_N + 1023) / 1024;         // 25 (<= 64 for scan_add butterfly)
    setup_misc<<<SETUP_BLKS, 256, 0, stream>>>(x, Hb, gin_w1, gin_w2, WThi, WTlo,
                                               batch, gstart, edst, cnts);
    scan_local<<<SCAN_BLKS, 1024, 0, stream>>>(cnts, off, bsum, SCAN_N);
    scan_add<<<SCAN_BLKS, 1024, 0, stream>>>(off, bsum, SCAN_N, N_EDGES);
    p3_place<<<B_CHUNK, 256, 0, stream>>>(esrc, edst, off, ebuf);
    p4_csr<<<NB, 512, 0, stream>>>(ebuf, off, eoff, csr);

    const int mm_grid = (N_NODES + 255) / 256;  // 196 blocks <= 256 CUs
    for (int l = 0; l < N_LAYERS; ++l) {
        agg_bf16<<<(N_NODES + 3) / 4, 256, 0, stream>>>((const uint4*)Hb, eoff, csr, (uint4*)Tb);
        mm_layer<<<mm_grid, 512, 0, stream>>>((const ushort_t*)Tb,
            WThi + (size_t)(2 * l) * DIM * DIM, WTlo + (size_t)(2 * l) * DIM * DIM,
            WThi + (size_t)(2 * l + 1) * DIM * DIM, WTlo + (size_t)(2 * l + 1) * DIM * DIM,
            gin_b1 + l * DIM, gin_b2 + l * DIM, (ushort_t*)Zb);
        if (l == N_LAYERS - 1)
            gn_last<<<N_GRAPHS, 1024, 0, stream>>>(Zb, gstart, gn_s + l * DIM,
                gn_w + l * DIM, gn_b + l * DIM, fw1, fb1, fw2, fb2, fw3, fb3, out);
        else
            gn_fused<<<N_GRAPHS * 2, 1024, 0, stream>>>(Zb, gstart, gn_s + l * DIM,
                gn_w + l * DIM, gn_b + l * DIM, Hb);
    }
}